// Round 18
// baseline (438.983 us; speedup 1.0000x reference)
//
#include <hip/hip_runtime.h>

// Soft-DTW (gamma=1), batched 64 x (1024 vs 1024, 2-D points).
//
// === R18: "R12 done right" -- 128 CUs x 2 waves/SIMD, spill-free ===
// R17 post-mortem: asm pins were NULL (VGPR stayed 56 -- compiler
// rematerializes pure loads/exp2 past pins); champion R17 = 315us with
// per-CU VALU busy ~71% but only 64/256 CUs working. Issue is the floor on
// the active CUs, so spread it: PARTS=2 x 64 batches = 128 blocks x 8 waves
// (512 thr, 1 row/lane), 2 waves/SIMD on 128 CUs -> per-SIMD issue halves.
// R12 tried this and regressed -- because its arrays were scratch-spilled
// (WRITE_SIZE=2.5MB was scratch). Here: k2 as f32[16] (16 VGPR), vr f64[16]
// (32), NO wb[] (per-step publish), ~85-110 VGPR total -> no spill.
// Partner blocks b and 64+b share an XCD (b%8 equal under round-robin).
//
// Geometry: global wave w = part*8 + wl in [0,16); wave w owns rows
// [64w, 64w+64); skew K=16 diagonals per wave; NGRP=143. One boundary per
// batch: part0 wave7 (w=7) publishes to part1 wave0 (w=8) via RELAXED
// agent-scope atomics (LLC-coherent, no cache maintenance -- R10->R11 fix):
// per-step value stores + off -> [rescale] -> vmcnt(0) -> flag=g. Reader
// prefetches raw at epoch-g bottom (need=g, poll+compiler-barrier+loads),
// converts at epoch-g+1 top. WLAST(8)=102; need>WLAST zero-fills (feeds
// only inactive cells). Intra-block boundaries: LDS parity ring (reader
// epoch g reads writer epoch g-1, parity (g^1)&1; overwrite 2 barriers
// later). One __syncthreads per epoch.
//
// Core (verified absmax 0.0 since R8): exp2-domain Z = 2^(off - R*log2e);
//   Z_d[i] = 2^(-D*log2e) * (Zdiag + Zup + Zleft)
// Per-cell op order bit-identical: zn = k2 * ((nb2 + nb1) + cur); zero
// transcendentals on-chain (k2 factors f32-computed, widened exactly);
// per-wave exact power-of-2 rescale per epoch (DPP max-reduce, pure VALU);
// lane-0 neighbor values converted by exact 2^(off-oin) two-stage factors;
// final cell (row 1023, diag 2046) snapshotted at its own step (exact);
// R = (res_off - log2(res)) * ln2; one atomicAdd per batch.

#define N 1024
#define PARTS 2
#define TPB 512
#define WPB 8                                  // waves per block
#define NW_G (PARTS * WPB)                     // 16 global waves
#define K 16                                   // diagonals per epoch
#define SLOTS 8                                // cross-block ring depth
#define NBND 1                                 // one boundary per batch
#define NGRP ((64 * (NW_G - 1) + 1084 + K * (NW_G - 1)) / K + 1)   // 143
#define L2E 1.442695040888963f
#define LN2D 0.6931471805599453

// workspace: vals[64][SLOTS][K+1] int64, then flags[64] int64
#define VALS_LL (64 * SLOTS * (K + 1))
#define WS_BYTES (VALS_LL * 8 + 64 * 8)

__device__ __forceinline__ float sqdist2(float2 a, float2 b) {
    float dx = a.x - b.x;
    float dy = a.y - b.y;
    return dx * dx + dy * dy;
}

// 64-bit DPP move (two 32-bit halves, same lane pattern; invalid lanes -> 0).
template <int CTRL>
__device__ __forceinline__ double dpp_movd(double src) {
    long long s = __double_as_longlong(src);
    int lo = __builtin_amdgcn_update_dpp(0, (int)(s & 0xffffffffLL),
                                         CTRL, 0xF, 0xF, false);
    int hi = __builtin_amdgcn_update_dpp(0, (int)(s >> 32),
                                         CTRL, 0xF, 0xF, false);
    return __longlong_as_double(((long long)hi << 32) | (unsigned int)lo);
}

template <int CTRL>
__device__ __forceinline__ int dpp_maxstep(int x) {
    int s = __builtin_amdgcn_update_dpp(0, x, CTRL, 0xF, 0xF, false);
    return max(x, s);
}

// Full 64-lane max of a nonneg int, pure VALU (no LDS); result wave-uniform.
__device__ __forceinline__ int wave_max_i(int x) {
    x = dpp_maxstep<0x111>(x);   // row_shr:1
    x = dpp_maxstep<0x112>(x);   // row_shr:2
    x = dpp_maxstep<0x114>(x);   // row_shr:4
    x = dpp_maxstep<0x118>(x);   // row_shr:8
    x = dpp_maxstep<0x142>(x);   // row_bcast15
    x = dpp_maxstep<0x143>(x);   // row_bcast31
    return __builtin_amdgcn_readlane(x, 63);
}

// exact 2^s as double for s in [-1022, 1023]
__device__ __forceinline__ double pow2d(int s) {
    return __longlong_as_double((long long)(1023 + s) << 52);
}

__global__ __launch_bounds__(TPB, 2) void dtw_kernel(
    const float2* __restrict__ snake,
    const float2* __restrict__ contour,
    float* __restrict__ out,
    long long* __restrict__ wsv,
    long long* __restrict__ wsf)
{
    const int t    = threadIdx.x;
    const int lane = t & 63;
    const int wl   = t >> 6;                 // local wave 0..7
    const int part = blockIdx.x >> 6;        // part-major: writers first
    const int b    = blockIdx.x & 63;        // batch
    const int w    = part * WPB + wl;        // global wave 0..15
    const int i    = (w << 6) + lane;        // global DP row

    __shared__ double ringv[WPB][2][K];      // intra-block boundary ring
    __shared__ int    ringo[WPB][2];
    __shared__ float  initvals[3];           // R0[0], R1[0], R1[1]

    const float2* sg = snake   + (size_t)b * N;
    const float2* cg = contour + (size_t)b * N;
    const float2 sp = sg[i];                 // snake point: register-resident

    if (t < WPB * 2 * K) ((double*)ringv)[t] = 0.0;   // Z(INF) = 0
    if (t < WPB * 2)     ((int*)ringo)[t] = 0;
    if (part == 0 && t == 0) {
        // Diagonals 0 and 1 (reference `init`):
        float2 s0 = sg[0], s1 = sg[1], c0 = cg[0], c1 = cg[1];
        float d00 = sqdist2(s0, c0);
        initvals[0] = d00;
        initvals[1] = sqdist2(s0, c1) + d00;
        initvals[2] = sqdist2(s1, c0) + d00;
    }
    __syncthreads();

    // Z-state entering the wave's first executed step (off = 0):
    //   cur = Z_{d-1}[i], nb1 = Z_{d-1}[i-1], nb2 = Z_{d-2}[i-1]
    double cur = 0.0, nb1 = 0.0, nb2 = 0.0;
    int off = 0;
    bool adopted = (w == 0);
    if (part == 0) {
        if (t == 0) {
            cur = (double)__builtin_amdgcn_exp2f(-L2E * initvals[1]);
        } else if (t == 1) {
            cur = (double)__builtin_amdgcn_exp2f(-L2E * initvals[2]);
            nb1 = (double)__builtin_amdgcn_exp2f(-L2E * initvals[1]);
            nb2 = (double)__builtin_amdgcn_exp2f(-L2E * initvals[0]);
        } else if (t == 2) {
            nb1 = (double)__builtin_amdgcn_exp2f(-L2E * initvals[2]);
        }
    }

    double res = 1.0;                        // final-cell snapshot (my row)
    int res_off = 0;

    const int lo = (w == 0) ? 2 : (64 * w - 1);   // -1 pre-step seeds nb1
    const int hi = 64 * w + 63 + (N - 1);
    // Writer (global wave w-1) last publishing epoch.
    const int WLAST = (w > 0) ? ((64 * (w - 1) + 1084) / K + (w - 1)) : 0;
    int d0 = 2 - K * w;

    float  k2[K];                            // step factors, f32 (16 VGPR)
    double vr[K];                            // neighbor boundary values:
                                             //   wl>0: filled at top (LDS)
                                             //   wl=0: raw prefetch, converted
    #pragma unroll                           //         in place at top
    for (int k = 0; k < K; ++k) vr[k] = 0.0;
    int oin_p = 0;

    const bool lds_pub = (wl < WPB - 1);                  // wave-uniform
    const bool glb_pub = (wl == WPB - 1) && (part == 0);

    long long* vout = wsv + (size_t)b * SLOTS * (K + 1);
    const long long* vin = vout;             // single boundary per batch
    const long long* fin = wsf + b;
    long long* fout = wsf + b;

    // Epoch-0 factors (prologue; cold loads acceptable once).
    #pragma unroll
    for (int k = 0; k < K; ++k) {
        const unsigned u = (unsigned)(d0 + k - i);
        float2 c = cg[u & (N - 1)];
        float e = __builtin_amdgcn_exp2f(sqdist2(sp, c) * (-L2E));
        k2[k] = (u < (unsigned)N) ? e : 0.0f;
    }

    for (int g = 0; g < NGRP; ++g) {
        const bool overlap = (d0 <= hi) && (d0 + (K - 1) >= lo);
        if (overlap) {
            long long* q = vout + (size_t)(g & (SLOTS - 1)) * (K + 1);

            if (w > 0) {
                int oin;
                if (wl > 0) {
                    const int p = (g ^ 1) & 1;
                    oin = ringo[wl - 1][p];                // all lanes (LDS)
                    if (!adopted) { off = oin; adopted = true; }
                    if (lane == 0) {
                        int dl = off - oin;
                        int c1 = min(max(dl, -1022), 1022);
                        int c2 = min(max(dl - c1, -1022), 1022);
                        double f1 = pow2d(c1), f2 = pow2d(c2);
                        const double* qq = &ringv[wl - 1][p][0];
                        #pragma unroll
                        for (int k = 0; k < K; ++k)
                            vr[k] = (qq[k] * f1) * f2;
                    }
                } else {
                    int tmp = (lane == 0) ? oin_p : 0;
                    oin = __builtin_amdgcn_readlane(tmp, 0);  // broadcast
                    if (!adopted) { off = oin; adopted = true; }
                    if (lane == 0) {
                        int dl = off - oin;
                        int c1 = min(max(dl, -1022), 1022);
                        int c2 = min(max(dl - c1, -1022), 1022);
                        double f1 = pow2d(c1), f2 = pow2d(c2);
                        #pragma unroll
                        for (int k = 0; k < K; ++k)        // raw -> converted
                            vr[k] = (vr[k] * f1) * f2;
                    }
                }
            }

            const int kres = (i + N - 1) - d0;   // step of my row's last cell

            // The chain: add+add+mul (f64) + DPP + selects per step.
            // f32->f64 widening of k2 is exact (bit-identical).
            #pragma unroll
            for (int k = 0; k < K; ++k) {
                double zn = (double)k2[k] * ((nb2 + nb1) + cur);
                if (k == kres) { res = zn; res_off = off; }
                cur = zn;
                if (lane == 63) {                 // per-step publish
                    if (lds_pub) {
                        ringv[wl][g & 1][k] = zn;
                    } else if (glb_pub) {
                        __hip_atomic_store(q + k, __double_as_longlong(zn),
                                           __ATOMIC_RELAXED,
                                           __HIP_MEMORY_SCOPE_AGENT);
                    }
                }
                double a  = dpp_movd<0x111>(zn);   // row_shr:1
                double bc = dpp_movd<0x142>(zn);   // row_bcast15
                double up = ((lane & 15) == 0) ? bc : a;
                nb2 = nb1;
                nb1 = (lane == 0) ? vr[k] : up;
            }

            // Publish part 1: offsets (pre-rescale, matching the values).
            if (lane == 63) {
                if (lds_pub) {
                    ringo[wl][g & 1] = off;
                } else if (glb_pub) {
                    __hip_atomic_store(q + K, (long long)off,
                                       __ATOMIC_RELAXED,
                                       __HIP_MEMORY_SCOPE_AGENT);
                }
            }

            // Per-wave exact power-of-2 rescale (DPP max-reduce, no LDS);
            // overlaps the global-store drain.
            int e = (int)((__double_as_longlong(cur) >> 52) & 0x7FF);
            e = wave_max_i(e);
            if (e > 0) {
                int sh = 1023 - e;
                int c1 = min(max(sh, -1022), 1022);
                int c2 = min(max(sh - c1, -1022), 1022);
                double f1 = pow2d(c1), f2 = pow2d(c2);
                cur = (cur * f1) * f2;
                nb1 = (nb1 * f1) * f2;
                nb2 = (nb2 * f1) * f2;
                off += sh;
            }

            // Publish part 2: drain + flag (after rescale).
            if (lane == 63 && glb_pub) {
                asm volatile("s_waitcnt vmcnt(0)" ::: "memory");
                __hip_atomic_store(fout, (long long)g, __ATOMIC_RELAXED,
                                   __HIP_MEMORY_SCOPE_AGENT);
            }
        }

        d0 += K;

        // Epoch bottom: next-epoch factors (latency hidden by the
        // co-resident wave at 2 waves/SIMD).
        #pragma unroll
        for (int k = 0; k < K; ++k) {
            const unsigned u = (unsigned)(d0 + k - i);
            float2 c = cg[u & (N - 1)];
            float e = __builtin_amdgcn_exp2f(sqdist2(sp, c) * (-L2E));
            k2[k] = (u < (unsigned)N) ? e : 0.0f;
        }

        // Cross-block PREFETCH for epoch g+1 (reader = part1 wave0 only).
        if (wl == 0 && part == 1) {
            const bool nov = (d0 <= hi) && (d0 + (K - 1) >= lo);
            if (nov && lane == 0) {
                const int need = g;           // = (g+1) - 1
                if (need > WLAST) {
                    // Writer finished: values feed only inactive cells.
                    #pragma unroll
                    for (int k = 0; k < K; ++k) vr[k] = 0.0;
                    oin_p = off;              // zeros are offset-immune
                } else {
                    while (__hip_atomic_load(fin, __ATOMIC_RELAXED,
                                             __HIP_MEMORY_SCOPE_AGENT)
                           < (long long)need)
                        __builtin_amdgcn_s_sleep(2);
                    asm volatile("" ::: "memory");   // no hoist past poll
                    const long long* qq =
                        vin + (size_t)(need & (SLOTS - 1)) * (K + 1);
                    #pragma unroll
                    for (int k = 0; k < K; ++k)        // raw (converted @top)
                        vr[k] = __longlong_as_double(
                            __hip_atomic_load(qq + k, __ATOMIC_RELAXED,
                                              __HIP_MEMORY_SCOPE_AGENT));
                    oin_p = (int)__hip_atomic_load(qq + K, __ATOMIC_RELAXED,
                                                   __HIP_MEMORY_SCOPE_AGENT);
                }
            }
        }

        __syncthreads();
    }

    // Global row 1023 lives in part 1, t 511: res = Z of R[1023,1023].
    if (part == PARTS - 1 && t == TPB - 1) {
        double R = ((double)res_off - log2(res)) * LN2D;
        atomicAdd(out, (float)(R * (1.0 / 64.0)));
    }
}

extern "C" void kernel_launch(void* const* d_in, const int* in_sizes, int n_in,
                              void* d_out, int out_size, void* d_ws, size_t ws_size,
                              hipStream_t stream) {
    const float2* snake   = (const float2*)d_in[0];
    const float2* contour = (const float2*)d_in[1];
    float* out = (float*)d_out;
    // Harness re-poisons d_out to 0xAA before every timed launch.
    hipMemsetAsync(out, 0, sizeof(float), stream);
    // Cross-block flags must start at -1 (0xFF...) every launch.
    hipMemsetAsync(d_ws, 0xFF, WS_BYTES, stream);
    long long* wsv = (long long*)d_ws;
    long long* wsf = (long long*)((char*)d_ws + (size_t)VALS_LL * 8);
    dtw_kernel<<<PARTS * 64, TPB, 0, stream>>>(snake, contour, out, wsv, wsf);
}